// Round 8
// baseline (225.213 us; speedup 1.0000x reference)
//
#include <hip/hip_runtime.h>

#define N_NODES 100000
#define N_EDGES 1600000
#define D 64
#define N_BBOX 4096
#define CAP 64      // per-node slot capacity; deg ~ Poisson(16), P(>=64) ~ 1e-20
#define NBITW 3136  // words for N_NODES bits, padded
#define NTILE 1563  // ceil(N_NODES / 64) blocks for the fused layer-1

typedef short bf16x8 __attribute__((ext_vector_type(8)));
typedef float f32x4 __attribute__((ext_vector_type(4)));

__device__ __forceinline__ float readlane_f(float v, int l) {
  return __int_as_float(__builtin_amdgcn_readlane(__float_as_int(v), l));
}
__device__ __forceinline__ int bperm(int srclane, int v) {
  return __builtin_amdgcn_ds_bpermute(srclane << 2, v);
}
__device__ __forceinline__ float lrelu(float v) {
  return fmaxf(v, 0.01f * v);  // neg_slope 0.01 > 0
}
__device__ __forceinline__ bool testbit(const unsigned* bits, int i) {
  return (bits[i >> 5] >> (i & 31)) & 1u;
}
__device__ __forceinline__ short f2bf(float f) {  // RNE fp32 -> bf16
  unsigned u = __float_as_uint(f);
  u += 0x7FFFu + ((u >> 16) & 1u);
  return (short)(u >> 16);
}
__device__ __forceinline__ bf16x8 pack_bf8(float4 lo, float4 hi) {
  bf16x8 r;
  r[0] = f2bf(lo.x); r[1] = f2bf(lo.y); r[2] = f2bf(lo.z); r[3] = f2bf(lo.w);
  r[4] = f2bf(hi.x); r[5] = f2bf(hi.y); r[6] = f2bf(hi.z); r[7] = f2bf(hi.w);
  return r;
}

// ---- mark bbox nodes in both bitmasks (12.5 KB each -> L1-resident) ----
__global__ __launch_bounds__(256) void mark_kernel(const int* __restrict__ bbox,
                                                   unsigned* __restrict__ is_bbox_bits,
                                                   unsigned* __restrict__ needed_bits) {
  int t = blockIdx.x * blockDim.x + threadIdx.x;
  if (t < N_BBOX) {
    int n = bbox[t];
    unsigned m = 1u << (n & 31);
    atomicOr(&is_bbox_bits[n >> 5], m);
    atomicOr(&needed_bits[n >> 5], m);
  }
}

// ---- mark srcs of edges landing on bbox nodes ----
__global__ __launch_bounds__(256) void mark_needed_kernel(
    const int* __restrict__ src, const int* __restrict__ dst,
    const unsigned* __restrict__ is_bbox_bits, unsigned* __restrict__ needed_bits) {
  int e = blockIdx.x * blockDim.x + threadIdx.x;
  if (e >= N_EDGES) return;
  int d = dst[e];
  if (testbit(is_bbox_bits, d)) {  // ~4% of lanes; L1-hit filter
    int s = src[e];
    atomicOr(&needed_bits[s >> 5], 1u << (s & 31));
  }
}

// ---- per-node slot fill, filtered to needed dst (~50% of edges) ----
__global__ __launch_bounds__(256) void fill_kernel(const int* __restrict__ src,
                                                   const int* __restrict__ dst,
                                                   const unsigned* __restrict__ needed_bits,
                                                   int* __restrict__ cnt,
                                                   int* __restrict__ slots) {
  int e = blockIdx.x * blockDim.x + threadIdx.x;
  if (e >= N_EDGES) return;
  int d = dst[e];
  if (!testbit(needed_bits, d)) return;
  int p = atomicAdd(&cnt[d], 1);
  if (p < CAP) slots[(size_t)d * CAP + p] = src[e];
}

// ---- pre-transpose W1rel/W1root to bf16 [n][k] so B-frags are 16B loads ----
__global__ __launch_bounds__(256) void wprep_kernel(const float* __restrict__ W1rel,
                                                    const float* __restrict__ W1root,
                                                    short* __restrict__ wrelT,
                                                    short* __restrict__ wrootT) {
  int i = blockIdx.x * blockDim.x + threadIdx.x;
  if (i < D * D) {
    int n = i >> 6, k = i & 63;
    wrelT[n * D + k] = f2bf(W1rel[k * D + n]);
    wrootT[n * D + k] = f2bf(W1root[k * D + n]);
  }
}

// ---- layer-1 fused: gather (wave-private LDS tile) + MFMA dense ----
// Block = 64 nodes; wave w gathers nodes [64*b+16w, +16) into LDS rows
// (stride 68 floats: <=2-way banks), then MFMAs its own 16-node tile.
// mfma_f32_16x16x32_bf16 layouts (HW-verified): A[m=lane&15][k=quad*8+i],
// B[k=quad*8+i][n=lane&15], C col=lane&15 row=quad*4+reg.
// Non-needed rows: LDS garbage is finite bits, MFMA rows independent,
// stores masked by needed-bit -> never observed.
__global__ __launch_bounds__(256, 1) void layer1_fused_kernel(
    const float4* __restrict__ x4, const unsigned* __restrict__ needed_bits,
    const int* __restrict__ cnt, const int* __restrict__ slots,
    const short* __restrict__ wrelT, const short* __restrict__ wrootT,
    const float* __restrict__ b1, float* __restrict__ hbuf) {
  __shared__ float lds[64 * 68];
  const int lane = threadIdx.x & 63;
  const int w = threadIdx.x >> 6;
  const int g = lane >> 4, c = lane & 15;

  // B-fragments: direct contiguous bf16x8 loads from transposed W
  bf16x8 brel[2][4], broot[2][4];
#pragma unroll
  for (int kh = 0; kh < 2; kh++)
#pragma unroll
    for (int nt = 0; nt < 4; nt++) {
      const int nn = nt * 16 + c;
      const int kb = kh * 32 + g * 8;
      brel[kh][nt] = *(const bf16x8*)&wrelT[nn * D + kb];
      broot[kh][nt] = *(const bf16x8*)&wrootT[nn * D + kb];
    }
  float bj[4];
#pragma unroll
  for (int nt = 0; nt < 4; nt++) bj[nt] = b1[nt * 16 + c];

  const int node0 = blockIdx.x * 64 + w * 16;

  // ---- phase A: gather agg rows for this wave's 16 nodes ----
  for (int li = 0; li < 16; li++) {
    const int node = node0 + li;
    if (node >= N_NODES) break;
    if (!testbit(needed_bits, node)) continue;
    int n = cnt[node];
    n = (n > CAP) ? CAP : n;
    const int myslot = (lane < n) ? slots[(size_t)node * CAP + lane] : 0;

    float4 acc = make_float4(0.f, 0.f, 0.f, 0.f);
    for (int e0 = 0; e0 < n; e0 += 32) {  // 8 float4 loads in flight
      int idx[8], s[8];
      float4 v[8];
#pragma unroll
      for (int u = 0; u < 8; u++) {
        idx[u] = e0 + u * 4 + g;
        s[u] = bperm(idx[u], myslot);
      }
#pragma unroll
      for (int u = 0; u < 8; u++) {
        v[u] = make_float4(0.f, 0.f, 0.f, 0.f);
        if (idx[u] < n) v[u] = x4[(size_t)s[u] * 16 + c];
      }
#pragma unroll
      for (int u = 0; u < 8; u++) {
        acc.x += v[u].x; acc.y += v[u].y; acc.z += v[u].z; acc.w += v[u].w;
      }
    }
    acc.x += __shfl_xor(acc.x, 16); acc.y += __shfl_xor(acc.y, 16);
    acc.z += __shfl_xor(acc.z, 16); acc.w += __shfl_xor(acc.w, 16);
    acc.x += __shfl_xor(acc.x, 32); acc.y += __shfl_xor(acc.y, 32);
    acc.z += __shfl_xor(acc.z, 32); acc.w += __shfl_xor(acc.w, 32);
    // lane c (group 0) holds row elements 4c..4c+3
    if (g == 0) *(float4*)&lds[(w * 16 + li) * 68 + 4 * c] = acc;
  }
  __syncthreads();  // conservative: orders LDS writes before reads

  // ---- phase B: dense via MFMA on this wave's 16-node tile ----
  f32x4 acc2[4] = {};
  const int arow_base = (w * 16 + c) * 68;
  const int xnode = (node0 + c < N_NODES) ? node0 + c : N_NODES - 1;  // clamp OOB
  const float* xrow = (const float*)x4 + (size_t)xnode * D;
#pragma unroll
  for (int kh = 0; kh < 2; kh++) {
    const int kb = kh * 32 + g * 8;
    const float4 fa0 = *(const float4*)&lds[arow_base + kb];
    const float4 fa1 = *(const float4*)&lds[arow_base + kb + 4];
    const float4 fx0 = *(const float4*)(xrow + kb);
    const float4 fx1 = *(const float4*)(xrow + kb + 4);
    const bf16x8 a_agg = pack_bf8(fa0, fa1);
    const bf16x8 a_x = pack_bf8(fx0, fx1);
#pragma unroll
    for (int nt = 0; nt < 4; nt++) {
      acc2[nt] = __builtin_amdgcn_mfma_f32_16x16x32_bf16(a_agg, brel[kh][nt],
                                                         acc2[nt], 0, 0, 0);
      acc2[nt] = __builtin_amdgcn_mfma_f32_16x16x32_bf16(a_x, broot[kh][nt],
                                                         acc2[nt], 0, 0, 0);
    }
  }
#pragma unroll
  for (int r = 0; r < 4; r++) {
    const int node = node0 + g * 4 + r;
    if (node < N_NODES && testbit(needed_bits, node)) {
#pragma unroll
      for (int nt = 0; nt < 4; nt++)
        hbuf[(size_t)node * D + nt * 16 + c] = lrelu(acc2[nt][r] + bj[nt]);
    }
  }
}

// ---- layer-2: fused gather + dense, bbox rows only (fp32) ----
__global__ __launch_bounds__(256, 1) void layer2_kernel(
    const float4* __restrict__ h4, const int* __restrict__ cnt,
    const int* __restrict__ slots, const int* __restrict__ bbox,
    const float* __restrict__ W2rel, const float* __restrict__ b2,
    const float* __restrict__ W2root, float* __restrict__ out) {
  const int t = (blockIdx.x * blockDim.x + threadIdx.x) >> 6;
  if (t >= N_BBOX) return;
  const int lane = threadIdx.x & 63;
  const int g = lane >> 4, c = lane & 15;

  float wrel[D], wroot[D];
#pragma unroll
  for (int k = 0; k < D; k++) {
    wrel[k] = W2rel[k * D + lane];
    wroot[k] = W2root[k * D + lane];
  }
  const float bj = b2[lane];

  const int node = __builtin_amdgcn_readfirstlane(bbox[t]);
  int n = cnt[node];
  n = (n > CAP) ? CAP : n;
  const int myslot = (lane < n) ? slots[(size_t)node * CAP + lane] : 0;

  float4 acc = make_float4(0.f, 0.f, 0.f, 0.f);
  for (int e0 = 0; e0 < n; e0 += 32) {
    int idx[8], s[8];
    float4 v[8];
#pragma unroll
    for (int u = 0; u < 8; u++) {
      idx[u] = e0 + u * 4 + g;
      s[u] = bperm(idx[u], myslot);
    }
#pragma unroll
    for (int u = 0; u < 8; u++) {
      v[u] = make_float4(0.f, 0.f, 0.f, 0.f);
      if (idx[u] < n) v[u] = h4[(size_t)s[u] * 16 + c];
    }
#pragma unroll
    for (int u = 0; u < 8; u++) {
      acc.x += v[u].x; acc.y += v[u].y; acc.z += v[u].z; acc.w += v[u].w;
    }
  }
  acc.x += __shfl_xor(acc.x, 16); acc.y += __shfl_xor(acc.y, 16);
  acc.z += __shfl_xor(acc.z, 16); acc.w += __shfl_xor(acc.w, 16);
  acc.x += __shfl_xor(acc.x, 32); acc.y += __shfl_xor(acc.y, 32);
  acc.z += __shfl_xor(acc.z, 32); acc.w += __shfl_xor(acc.w, 32);

  const float hi = ((const float*)h4)[(size_t)node * D + lane];
  float s0 = 0.f, s1 = 0.f, s2 = 0.f, s3 = 0.f;
#pragma unroll
  for (int k = 0; k < D; k += 2) {
    const float a0 = (k & 2) ? readlane_f(acc.z, k >> 2) : readlane_f(acc.x, k >> 2);
    const float a1 = ((k + 1) & 2) ? readlane_f(acc.w, (k + 1) >> 2)
                                   : readlane_f(acc.y, (k + 1) >> 2);
    s0 += a0 * wrel[k];
    s1 += readlane_f(hi, k) * wroot[k];
    s2 += a1 * wrel[k + 1];
    s3 += readlane_f(hi, k + 1) * wroot[k + 1];
  }
  out[(size_t)t * D + lane] = lrelu(bj + ((s0 + s1) + (s2 + s3)));
}

// ---------------- launch ----------------

extern "C" void kernel_launch(void* const* d_in, const int* in_sizes, int n_in,
                              void* d_out, int out_size, void* d_ws, size_t ws_size,
                              hipStream_t stream) {
  const float* x = (const float*)d_in[0];
  const int* ei = (const int*)d_in[1];
  const int* src = ei;
  const int* dst = ei + N_EDGES;
  const int* bbox = (const int*)d_in[2];
  const float* W1rel = (const float*)d_in[3];
  const float* b1 = (const float*)d_in[4];
  const float* W1root = (const float*)d_in[5];
  const float* W2rel = (const float*)d_in[6];
  const float* b2 = (const float*)d_in[7];
  const float* W2root = (const float*)d_in[8];
  float* out = (float*)d_out;

  char* ws = (char*)d_ws;
  size_t off = 0;
  auto alloc = [&](size_t bytes) -> char* {
    char* p = ws + off;
    off = (off + bytes + 511) & ~(size_t)511;
    return p;
  };
  // contiguous zero region: bitmasks + cnt (~425 KB, one memset)
  unsigned* is_bbox_bits = (unsigned*)alloc(NBITW * sizeof(unsigned));
  unsigned* needed_bits = (unsigned*)alloc(NBITW * sizeof(unsigned));
  int* cnt = (int*)alloc(N_NODES * sizeof(int));
  char* zero_end = ws + off;
  int* slots = (int*)alloc((size_t)N_NODES * CAP * sizeof(int));    // 25.6 MB
  float* hbuf = (float*)alloc((size_t)N_NODES * D * sizeof(float)); // 25.6 MB
  short* wrelT = (short*)alloc(D * D * sizeof(short));
  short* wrootT = (short*)alloc(D * D * sizeof(short));

  hipMemsetAsync(is_bbox_bits, 0, (size_t)(zero_end - (char*)is_bbox_bits), stream);
  mark_kernel<<<(N_BBOX + 255) / 256, 256, 0, stream>>>(bbox, is_bbox_bits,
                                                        needed_bits);
  mark_needed_kernel<<<(N_EDGES + 255) / 256, 256, 0, stream>>>(
      src, dst, is_bbox_bits, needed_bits);
  fill_kernel<<<(N_EDGES + 255) / 256, 256, 0, stream>>>(src, dst, needed_bits,
                                                         cnt, slots);
  wprep_kernel<<<(D * D + 255) / 256, 256, 0, stream>>>(W1rel, W1root, wrelT,
                                                        wrootT);
  layer1_fused_kernel<<<NTILE, 256, 0, stream>>>(
      (const float4*)x, needed_bits, cnt, slots, wrelT, wrootT, b1, hbuf);
  layer2_kernel<<<(N_BBOX + 3) / 4, 256, 0, stream>>>(
      (const float4*)hbuf, cnt, slots, bbox, W2rel, b2, W2root, out);
}

// Round 9
// 206.153 us; speedup vs baseline: 1.0925x; 1.0925x over previous
//
#include <hip/hip_runtime.h>

#define N_NODES 100000
#define N_EDGES 1600000
#define D 64
#define N_BBOX 4096
#define CAP 64      // per-node slot capacity; deg ~ Poisson(16), P(>=64) ~ 1e-20
#define NBITW 3136  // words for N_NODES bits, padded
#define SLICE 12500 // N_NODES / 8 XCD slices; slots slice (3.2 MB) fits 4 MB L2

typedef short bf16x8 __attribute__((ext_vector_type(8)));
typedef float f32x4 __attribute__((ext_vector_type(4)));

__device__ __forceinline__ float readlane_f(float v, int l) {
  return __int_as_float(__builtin_amdgcn_readlane(__float_as_int(v), l));
}
__device__ __forceinline__ int bperm(int srclane, int v) {
  return __builtin_amdgcn_ds_bpermute(srclane << 2, v);
}
__device__ __forceinline__ float lrelu(float v) {
  return fmaxf(v, 0.01f * v);  // neg_slope 0.01 > 0
}
__device__ __forceinline__ bool testbit(const unsigned* bits, int i) {
  return (bits[i >> 5] >> (i & 31)) & 1u;
}
__device__ __forceinline__ short f2bf(float f) {  // RNE fp32 -> bf16
  unsigned u = __float_as_uint(f);
  u += 0x7FFFu + ((u >> 16) & 1u);
  return (short)(u >> 16);
}
__device__ __forceinline__ bf16x8 pack_bf8(float4 lo, float4 hi) {
  bf16x8 r;
  r[0] = f2bf(lo.x); r[1] = f2bf(lo.y); r[2] = f2bf(lo.z); r[3] = f2bf(lo.w);
  r[4] = f2bf(hi.x); r[5] = f2bf(hi.y); r[6] = f2bf(hi.z); r[7] = f2bf(hi.w);
  return r;
}

// ---- mark bbox nodes in both bitmasks (12.5 KB each -> L1-resident) ----
__global__ __launch_bounds__(256) void mark_kernel(const int* __restrict__ bbox,
                                                   unsigned* __restrict__ is_bbox_bits,
                                                   unsigned* __restrict__ needed_bits) {
  int t = blockIdx.x * blockDim.x + threadIdx.x;
  if (t < N_BBOX) {
    int n = bbox[t];
    unsigned m = 1u << (n & 31);
    atomicOr(&is_bbox_bits[n >> 5], m);
    atomicOr(&needed_bits[n >> 5], m);
  }
}

// ---- mark srcs of edges landing on bbox nodes ----
__global__ __launch_bounds__(256) void mark_needed_kernel(
    const int* __restrict__ src, const int* __restrict__ dst,
    const unsigned* __restrict__ is_bbox_bits, unsigned* __restrict__ needed_bits) {
  int e = blockIdx.x * blockDim.x + threadIdx.x;
  if (e >= N_EDGES) return;
  int d = dst[e];
  if (testbit(is_bbox_bits, d)) {  // ~4% of lanes; L1-hit filter
    int s = src[e];
    atomicOr(&needed_bits[s >> 5], 1u << (s & 31));
  }
}

// ---- XCD-sliced slot fill ----
// blockIdx%8 = presumed XCD (documented placement heuristic). Group g's blocks
// scan ALL edges (int4, lazy src4 load) but write only dst in slice g, so a
// slots line has ONE writing XCD: no cross-XCD line ping-pong, cnt atomics
// XCD-local, slice working set (3.2 MB slots + 50 KB cnt) L2-resident.
// Correctness independent of the %8->XCD mapping (wrong mapping = slow only).
__global__ __launch_bounds__(256) void fill_kernel(const int4* __restrict__ src4,
                                                   const int4* __restrict__ dst4,
                                                   const unsigned* __restrict__ needed_bits,
                                                   int* __restrict__ cnt,
                                                   int* __restrict__ slots) {
  const int grp = blockIdx.x & 7;
  const int bidx = blockIdx.x >> 3;
  const int nblk = gridDim.x >> 3;
  const int lo = grp * SLICE;
  const int hi = lo + SLICE;  // last slice: hi=100000 exactly
  const int nq = N_EDGES / 4;

  for (int q = bidx * blockDim.x + threadIdx.x; q < nq; q += nblk * blockDim.x) {
    const int4 d4 = dst4[q];
    const int dd[4] = {d4.x, d4.y, d4.z, d4.w};
    bool m[4], any = false;
#pragma unroll
    for (int u = 0; u < 4; u++) {
      m[u] = (dd[u] >= lo) & (dd[u] < hi);
      if (m[u]) m[u] = testbit(needed_bits, dd[u]);  // L1-hit filter
      any |= m[u];
    }
    if (!any) continue;
    const int4 s4 = src4[q];  // fetched only when a lane owns an edge
    const int ss[4] = {s4.x, s4.y, s4.z, s4.w};
#pragma unroll
    for (int u = 0; u < 4; u++) {
      if (!m[u]) continue;
      int p = atomicAdd(&cnt[dd[u]], 1);
      if (p < CAP) slots[(size_t)dd[u] * CAP + p] = ss[u];
    }
  }
}

// ---- layer-1 gather (needed nodes only): 4 edges/instr, 32 in flight ----
__global__ __launch_bounds__(256) void gather1_kernel(const float4* __restrict__ x4,
                                                      const unsigned* __restrict__ needed_bits,
                                                      const int* __restrict__ cnt,
                                                      const int* __restrict__ slots,
                                                      float4* __restrict__ agg4) {
  const int wid = (blockIdx.x * blockDim.x + threadIdx.x) >> 6;
  if (wid >= N_NODES) return;
  if (!testbit(needed_bits, wid)) return;
  const int lane = threadIdx.x & 63;
  const int g = lane >> 4, c = lane & 15;

  int n = cnt[wid];
  n = (n > CAP) ? CAP : n;
  const int myslot = (lane < n) ? slots[(size_t)wid * CAP + lane] : 0;

  float4 acc = make_float4(0.f, 0.f, 0.f, 0.f);
  for (int e0 = 0; e0 < n; e0 += 32) {
    int idx[8], s[8];
    float4 v[8];
#pragma unroll
    for (int u = 0; u < 8; u++) {
      idx[u] = e0 + u * 4 + g;
      s[u] = bperm(idx[u], myslot);
    }
#pragma unroll
    for (int u = 0; u < 8; u++) {
      v[u] = make_float4(0.f, 0.f, 0.f, 0.f);
      if (idx[u] < n) v[u] = x4[(size_t)s[u] * 16 + c];
    }
#pragma unroll
    for (int u = 0; u < 8; u++) {
      acc.x += v[u].x; acc.y += v[u].y; acc.z += v[u].z; acc.w += v[u].w;
    }
  }
  acc.x += __shfl_xor(acc.x, 16); acc.y += __shfl_xor(acc.y, 16);
  acc.z += __shfl_xor(acc.z, 16); acc.w += __shfl_xor(acc.w, 16);
  acc.x += __shfl_xor(acc.x, 32); acc.y += __shfl_xor(acc.y, 32);
  acc.z += __shfl_xor(acc.z, 32); acc.w += __shfl_xor(acc.w, 32);
  if (g == 0) agg4[(size_t)wid * 16 + c] = acc;
}

// ---- layer-1 dense via MFMA: h = lrelu(agg@W1rel + b1 + x@W1root), in place ----
// One wave per 16-node tile (grid-stride). mfma_f32_16x16x32_bf16 layouts
// (HW-verified): A[m=lane&15][k=quad*8+i], B[k=quad*8+i][n=lane&15],
// C col=lane&15, row=quad*4+reg. Runs over ALL tiles (needed-density ~50%).
__global__ __launch_bounds__(256, 1) void dense1_mfma_kernel(
    const float* __restrict__ x, const float* __restrict__ W1rel,
    const float* __restrict__ b1, const float* __restrict__ W1root,
    float* __restrict__ hbuf) {
  const int lane = threadIdx.x & 63;
  const int cn = lane & 15;
  const int quad = lane >> 4;
  const int wid0 = (blockIdx.x * blockDim.x + threadIdx.x) >> 6;
  const int nwaves = (gridDim.x * blockDim.x) >> 6;

  bf16x8 brel[2][4], broot[2][4];
#pragma unroll
  for (int kh = 0; kh < 2; kh++)
#pragma unroll
    for (int nt = 0; nt < 4; nt++)
#pragma unroll
      for (int i = 0; i < 8; i++) {
        const int k = kh * 32 + quad * 8 + i;
        brel[kh][nt][i] = f2bf(W1rel[k * D + nt * 16 + cn]);
        broot[kh][nt][i] = f2bf(W1root[k * D + nt * 16 + cn]);
      }
  float bj[4];
#pragma unroll
  for (int nt = 0; nt < 4; nt++) bj[nt] = b1[nt * 16 + cn];

  for (int tile = wid0; tile < N_NODES / 16; tile += nwaves) {
    const int node0 = tile * 16;
    const float* arow = hbuf + (size_t)(node0 + cn) * D;
    const float* xrow = x + (size_t)(node0 + cn) * D;

    f32x4 acc[4] = {};
#pragma unroll
    for (int kh = 0; kh < 2; kh++) {
      const int kb = kh * 32 + quad * 8;
      const float4 fa0 = *(const float4*)(arow + kb);
      const float4 fa1 = *(const float4*)(arow + kb + 4);
      const float4 fx0 = *(const float4*)(xrow + kb);
      const float4 fx1 = *(const float4*)(xrow + kb + 4);
      const bf16x8 a_agg = pack_bf8(fa0, fa1);
      const bf16x8 a_x = pack_bf8(fx0, fx1);
#pragma unroll
      for (int nt = 0; nt < 4; nt++) {
        acc[nt] = __builtin_amdgcn_mfma_f32_16x16x32_bf16(a_agg, brel[kh][nt],
                                                          acc[nt], 0, 0, 0);
        acc[nt] = __builtin_amdgcn_mfma_f32_16x16x32_bf16(a_x, broot[kh][nt],
                                                          acc[nt], 0, 0, 0);
      }
    }
#pragma unroll
    for (int nt = 0; nt < 4; nt++) {
#pragma unroll
      for (int r = 0; r < 4; r++) {
        const int row = quad * 4 + r;
        hbuf[(size_t)(node0 + row) * D + nt * 16 + cn] = lrelu(acc[nt][r] + bj[nt]);
      }
    }
  }
}

// ---- layer-2: fused gather + dense, bbox rows only (fp32) ----
__global__ __launch_bounds__(256, 1) void layer2_kernel(
    const float4* __restrict__ h4, const int* __restrict__ cnt,
    const int* __restrict__ slots, const int* __restrict__ bbox,
    const float* __restrict__ W2rel, const float* __restrict__ b2,
    const float* __restrict__ W2root, float* __restrict__ out) {
  const int t = (blockIdx.x * blockDim.x + threadIdx.x) >> 6;
  if (t >= N_BBOX) return;
  const int lane = threadIdx.x & 63;
  const int g = lane >> 4, c = lane & 15;

  float wrel[D], wroot[D];
#pragma unroll
  for (int k = 0; k < D; k++) {
    wrel[k] = W2rel[k * D + lane];
    wroot[k] = W2root[k * D + lane];
  }
  const float bj = b2[lane];

  const int node = __builtin_amdgcn_readfirstlane(bbox[t]);
  int n = cnt[node];
  n = (n > CAP) ? CAP : n;
  const int myslot = (lane < n) ? slots[(size_t)node * CAP + lane] : 0;

  float4 acc = make_float4(0.f, 0.f, 0.f, 0.f);
  for (int e0 = 0; e0 < n; e0 += 32) {
    int idx[8], s[8];
    float4 v[8];
#pragma unroll
    for (int u = 0; u < 8; u++) {
      idx[u] = e0 + u * 4 + g;
      s[u] = bperm(idx[u], myslot);
    }
#pragma unroll
    for (int u = 0; u < 8; u++) {
      v[u] = make_float4(0.f, 0.f, 0.f, 0.f);
      if (idx[u] < n) v[u] = h4[(size_t)s[u] * 16 + c];
    }
#pragma unroll
    for (int u = 0; u < 8; u++) {
      acc.x += v[u].x; acc.y += v[u].y; acc.z += v[u].z; acc.w += v[u].w;
    }
  }
  acc.x += __shfl_xor(acc.x, 16); acc.y += __shfl_xor(acc.y, 16);
  acc.z += __shfl_xor(acc.z, 16); acc.w += __shfl_xor(acc.w, 16);
  acc.x += __shfl_xor(acc.x, 32); acc.y += __shfl_xor(acc.y, 32);
  acc.z += __shfl_xor(acc.z, 32); acc.w += __shfl_xor(acc.w, 32);

  const float hi = ((const float*)h4)[(size_t)node * D + lane];
  float s0 = 0.f, s1 = 0.f, s2 = 0.f, s3 = 0.f;
#pragma unroll
  for (int k = 0; k < D; k += 2) {
    const float a0 = (k & 2) ? readlane_f(acc.z, k >> 2) : readlane_f(acc.x, k >> 2);
    const float a1 = ((k + 1) & 2) ? readlane_f(acc.w, (k + 1) >> 2)
                                   : readlane_f(acc.y, (k + 1) >> 2);
    s0 += a0 * wrel[k];
    s1 += readlane_f(hi, k) * wroot[k];
    s2 += a1 * wrel[k + 1];
    s3 += readlane_f(hi, k + 1) * wroot[k + 1];
  }
  out[(size_t)t * D + lane] = lrelu(bj + ((s0 + s1) + (s2 + s3)));
}

// ---------------- launch ----------------

extern "C" void kernel_launch(void* const* d_in, const int* in_sizes, int n_in,
                              void* d_out, int out_size, void* d_ws, size_t ws_size,
                              hipStream_t stream) {
  const float* x = (const float*)d_in[0];
  const int* ei = (const int*)d_in[1];
  const int* src = ei;
  const int* dst = ei + N_EDGES;
  const int* bbox = (const int*)d_in[2];
  const float* W1rel = (const float*)d_in[3];
  const float* b1 = (const float*)d_in[4];
  const float* W1root = (const float*)d_in[5];
  const float* W2rel = (const float*)d_in[6];
  const float* b2 = (const float*)d_in[7];
  const float* W2root = (const float*)d_in[8];
  float* out = (float*)d_out;

  char* ws = (char*)d_ws;
  size_t off = 0;
  auto alloc = [&](size_t bytes) -> char* {
    char* p = ws + off;
    off = (off + bytes + 511) & ~(size_t)511;
    return p;
  };
  // contiguous zero region: bitmasks + cnt (~425 KB, one memset)
  unsigned* is_bbox_bits = (unsigned*)alloc(NBITW * sizeof(unsigned));
  unsigned* needed_bits = (unsigned*)alloc(NBITW * sizeof(unsigned));
  int* cnt = (int*)alloc(N_NODES * sizeof(int));
  char* zero_end = ws + off;
  int* slots = (int*)alloc((size_t)N_NODES * CAP * sizeof(int));    // 25.6 MB
  float* hbuf = (float*)alloc((size_t)N_NODES * D * sizeof(float)); // 25.6 MB

  hipMemsetAsync(is_bbox_bits, 0, (size_t)(zero_end - (char*)is_bbox_bits), stream);
  mark_kernel<<<(N_BBOX + 255) / 256, 256, 0, stream>>>(bbox, is_bbox_bits,
                                                        needed_bits);
  mark_needed_kernel<<<(N_EDGES + 255) / 256, 256, 0, stream>>>(
      src, dst, is_bbox_bits, needed_bits);
  fill_kernel<<<1024, 256, 0, stream>>>((const int4*)src, (const int4*)dst,
                                        needed_bits, cnt, slots);
  gather1_kernel<<<(N_NODES + 3) / 4, 256, 0, stream>>>(
      (const float4*)x, needed_bits, cnt, slots, (float4*)hbuf);
  dense1_mfma_kernel<<<512, 256, 0, stream>>>(x, W1rel, b1, W1root, hbuf);
  layer2_kernel<<<(N_BBOX + 3) / 4, 256, 0, stream>>>(
      (const float4*)hbuf, cnt, slots, bbox, W2rel, b2, W2root, out);
}